// Round 19
// baseline (279.616 us; speedup 1.0000x reference)
//
#include <hip/hip_runtime.h>

// ResidualNetwork forward, MI355X (gfx950).
// Round 19: r18's per-operand-class asm MFMA (A="a" AGPR-resident weights,
// B/C/D="v") + the missing HAZARD NOPS. r18 failed (absmax 0.6) because the
// compiler's hazard recognizer does not protect opaque asm: 16-pass MFMA dst
// needs ~18 wait states before VALU may read it; VALU writes need ~2 cycles
// before an MFMA reads them. Fix: bake the nops into the asm blocks and pair
// both ILP chains per block to share the tail:
//   s_nop 3 | mfma d0 | mfma d1 | s_nop 7 x3
// Per tile: 17 blocks x ~46 cyc stall + ~500 VALU ~= 1300 cyc serial (r17
// measured ~2500). Stalls are wave-local -> overlap across ~2 resident waves.
// Chain unchanged (r13): sigma-permuted K (D dwords ARE next B fragment),
// ones-row bias, ILP=2, launch_bounds(256,2).
// Gates: absmax passes; VALU busy cyc >=3x down vs r17; FETCH ~24.8MB flat.

#define NPTS 4194304
#define NBLK 2048
#define NWAVES (NBLK * 4)           // 8192
#define NTILES (NPTS / 32)          // 131072
#define TPW (NTILES / NWAVES)       // 16 tiles per wave
#define NMM 34
#define ILP 2

typedef _Float16 h8 __attribute__((ext_vector_type(8)));
typedef float v8f __attribute__((ext_vector_type(8)));
typedef float v16f __attribute__((ext_vector_type(16)));
typedef unsigned u4v __attribute__((ext_vector_type(4)));

// Two independent D = A*B + zero, one hazard-guarded block.
// s_nop 3 guards VALU-write -> MFMA-read of B; s_nop 7 x3 guards the 16-pass
// MFMA-write -> any-read distance for the LAST mfma (first has extra slack).
__device__ __forceinline__ void mmz2(h8 a, h8 b0, h8 b1, const v16f& c,
                                     v16f& d0, v16f& d1) {
    asm volatile("s_nop 3\n\t"
                 "v_mfma_f32_32x32x16_f16 %0, %2, %3, %5\n\t"
                 "v_mfma_f32_32x32x16_f16 %1, %2, %4, %5\n\t"
                 "s_nop 7\n\t s_nop 7\n\t s_nop 7"
                 : "=&v"(d0), "=&v"(d1)
                 : "a"(a), "v"(b0), "v"(b1), "v"(c));
}
// Two independent D += A*B (srcC/dst tied, HW-native accumulate).
__device__ __forceinline__ void mmacc2(h8 a, h8 b0, h8 b1,
                                       v16f& d0, v16f& d1) {
    asm volatile("s_nop 3\n\t"
                 "v_mfma_f32_32x32x16_f16 %0, %2, %3, %0\n\t"
                 "v_mfma_f32_32x32x16_f16 %1, %2, %4, %1\n\t"
                 "s_nop 7\n\t s_nop 7\n\t s_nop 7"
                 : "+v"(d0), "+v"(d1)
                 : "a"(a), "v"(b0), "v"(b1));
}
__device__ __forceinline__ unsigned pkrtz(float a, float b) {
    return __builtin_bit_cast(unsigned, __builtin_amdgcn_cvt_pkrtz(a, b));
}
// relu + pack-cvt of the 8 live D regs; output IS next layer's B (sigma order)
__device__ __forceinline__ h8 rc(v16f d) {
    v8f lo8 = __builtin_shufflevector(d, d, 0, 1, 2, 3, 4, 5, 6, 7);
    v8f z8 = {0.f, 0.f, 0.f, 0.f, 0.f, 0.f, 0.f, 0.f};
    v8f m = __builtin_elementwise_max(lo8, z8);
    u4v u;
    u.x = pkrtz(m[0], m[1]);
    u.y = pkrtz(m[2], m[3]);
    u.z = pkrtz(m[4], m[5]);
    u.w = pkrtz(m[6], m[7]);
    return __builtin_bit_cast(h8, u);
}

// ---------------- prepack: A fragments, sigma-permuted K (one block per q) ---
__global__ __launch_bounds__(64) void prepack(
    const float* __restrict__ w0, const float* __restrict__ b0,
    const float* __restrict__ w1, const float* __restrict__ b1,
    const float* __restrict__ Wr1, const float* __restrict__ Br1,
    const float* __restrict__ Wr2, const float* __restrict__ Br2,
    const float* __restrict__ Wr3, const float* __restrict__ Br3,
    const float* __restrict__ w8, const float* __restrict__ b8,
    const float* __restrict__ w9, const float* __restrict__ b9,
    h8* __restrict__ tab)
{
    const int q = blockIdx.x, l = threadIdx.x;
    const int m = l & 31, g = l >> 5;
    h8 v;
#pragma unroll
    for (int j = 0; j < 8; ++j) {
        const int rr = (j & 3) + 8 * (j >> 2) + 4 * g;  // sigma(k)
        float a = 0.0f;
        if (q == 0) {
            if (m < 10 && rr < 3)        a = w0[rr * 10 + m];
            else if (m < 10 && rr == 3)  a = b0[m];
            else if (m == 10 && rr == 3) a = 1.0f;
        } else if (q == 33) {
            if (m == 0 && rr < 10)       a = w9[rr];
            else if (m == 0 && rr == 10) a = b9[0];
        } else {
            const float* W = nullptr;
            float bias = 0.0f;
            bool hasB = true, pass = true;
            if (q == 1)       { W = w1; bias = (m < 10) ? b1[m] : 0.0f; }
            else if (q == 32) { W = w8; bias = (m < 10) ? b8[m] : 0.0f; }
            else {
                const int qq = q - 2, bl = qq / 3, r = qq % 3;
                if (r == 0)      { W = Wr1 + bl * 100; bias = (m < 10) ? Br1[bl * 10 + m] : 0.0f; }
                else if (r == 1) { W = Wr2 + bl * 100; bias = (m < 10) ? Br2[bl * 10 + m] + Br3[bl * 10 + m] : 0.0f; }
                else             { W = Wr3 + bl * 100; hasB = false; pass = false; }
            }
            if (m < 10 && rr < 10)                a = W[rr * 10 + m];
            else if (m < 10 && rr == 10 && hasB)  a = bias;
            else if (m == 10 && rr == 10 && pass) a = 1.0f;
        }
        v[j] = (_Float16)a;
    }
    tab[q * 64 + l] = v;
}

// ---------------- main kernel: AGPR weights, VGPR accs, guarded asm ----------
__global__ __launch_bounds__(256, 2) void resnet_fwd(
    const float* __restrict__ x,
    const h8* __restrict__ tab,
    float* __restrict__ out)
{
    const int lane = threadIdx.x & 63;
    const int wv = blockIdx.x * 4 + (threadIdx.x >> 6);
    const int col = lane & 31;
    const bool lo = lane < 32;

    // preload weight fragments, pin into AGPRs (one-time copy per wave)
    h8 wA[NMM];
#pragma unroll
    for (int q = 0; q < NMM; ++q) wA[q] = tab[q * 64 + lane];
#pragma unroll
    for (int q = 0; q < NMM; ++q) asm volatile("" : "+a"(wA[q]));

    // zero srcC resident in VGPRs
    v16f zero;
#pragma unroll
    for (int j = 0; j < 16; ++j) zero[j] = 0.0f;
    asm volatile("" : "+v"(zero));

    const long tile0 = (long)wv * TPW;

    for (int t = 0; t < TPW; t += ILP) {
        long base0 = (tile0 + t) * 32;
        long base1 = (tile0 + t + 1) * 32;
        h8 hh0, hh1;

        // layer-0 B: lanes 0-31 carry (x0,x1,x2,1) in k-rows 0-3; rest zero
        {
            float a0 = 0.f, a1 = 0.f, a2 = 0.f, a3 = 0.f;
            float c0 = 0.f, c1 = 0.f, c2 = 0.f, c3 = 0.f;
            if (lo) {
                const float* p0 = x + (base0 + col) * 3;
                a0 = p0[0]; a1 = p0[1]; a2 = p0[2]; a3 = 1.0f;
                const float* p1 = x + (base1 + col) * 3;
                c0 = p1[0]; c1 = p1[1]; c2 = p1[2]; c3 = 1.0f;
            }
            u4v u;
            u.x = pkrtz(a0, a1); u.y = pkrtz(a2, a3); u.z = 0u; u.w = 0u;
            hh0 = __builtin_bit_cast(h8, u);
            u.x = pkrtz(c0, c1); u.y = pkrtz(c2, c3);
            hh1 = __builtin_bit_cast(h8, u);
        }

        v16f d0, d1;
        // layer 0, layer 1
        mmz2(wA[0], hh0, hh1, zero, d0, d1);
        hh0 = rc(d0); hh1 = rc(d1);
        mmz2(wA[1], hh0, hh1, zero, d0, d1);
        hh0 = rc(d0); hh1 = rc(d1);

        // residual blocks
#pragma unroll
        for (int bl = 0; bl < 10; ++bl) {
            v16f e0, e1;
            mmz2(wA[2 + 3 * bl], hh0, hh1, zero, d0, d1);   // h@W1+B1
            h8 t10 = rc(d0), t11 = rc(d1);
            mmz2(wA[3 + 3 * bl], hh0, hh1, zero, e0, e1);   // h@W2+B23
            mmacc2(wA[4 + 3 * bl], t10, t11, e0, e1);       // += t1@W3
            hh0 = rc(e0); hh1 = rc(e1);
        }

        // layer 8
        mmz2(wA[32], hh0, hh1, zero, d0, d1);
        hh0 = rc(d0); hh1 = rc(d1);

        // output layer: D row 0 (lanes 0-31, reg 0) = result for 32 points
        mmz2(wA[33], hh0, hh1, zero, d0, d1);
        if (lo) {
            out[base0 + col] = d0[0];
            out[base1 + col] = d1[0];
        }
    }
}

extern "C" void kernel_launch(void* const* d_in, const int* in_sizes, int n_in,
                              void* d_out, int out_size, void* d_ws, size_t ws_size,
                              hipStream_t stream)
{
    const float* x   = (const float*)d_in[0];
    const float* w0  = (const float*)d_in[1];
    const float* b0  = (const float*)d_in[2];
    const float* w1  = (const float*)d_in[3];
    const float* b1  = (const float*)d_in[4];
    const float* Wr1 = (const float*)d_in[5];
    const float* Br1 = (const float*)d_in[6];
    const float* Wr2 = (const float*)d_in[7];
    const float* Br2 = (const float*)d_in[8];
    const float* Wr3 = (const float*)d_in[9];
    const float* Br3 = (const float*)d_in[10];
    const float* w8  = (const float*)d_in[11];
    const float* b8  = (const float*)d_in[12];
    const float* w9  = (const float*)d_in[13];
    const float* b9  = (const float*)d_in[14];
    float* out = (float*)d_out;
    h8* tab = (h8*)d_ws;   // 34 * 64 * 16B = 34.8 KB scratch

    hipLaunchKernelGGL(prepack, dim3(NMM), dim3(64), 0, stream,
                       w0, b0, w1, b1, Wr1, Br1, Wr2, Br2, Wr3, Br3,
                       w8, b8, w9, b9, tab);

    hipLaunchKernelGGL(resnet_fwd, dim3(NBLK), dim3(256), 0, stream,
                       x, (const h8*)tab, out);
}

// Round 20
// 234.708 us; speedup vs baseline: 1.1913x; 1.1913x over previous
//
#include <hip/hip_runtime.h>

// ResidualNetwork forward, MI355X (gfx950).
// Round 20: LAYER FUSION in the 32x32 tile. r12-r19 invariant: per-SIMD busy
// ~270-300k cyc regardless of shape/ILP/classes/asm; MfmaUtil*dur gives
// ~33 cyc occupied per 32x32x16 MFMA (latency + per-MFMA srcC/staging tax at
// ~2 waves/SIMD). Lever: fewer MFMAs. A uses 11 of 32 rows; W1,W2 multiply
// the SAME h -> stack A=[W1^T+B1 rows0-10 ; W2^T+B23 rows16-26]: ONE MFMA
// yields t1-pre (regs0-7) AND t2-partial (regs8-15) since row 16+r sits at
// reg+8 (row=(reg&3)+8(reg>>2)+4g). Second MFMA: W3^T in A rows16-26,
// srcC=d12 -> accumulates rows16-26 in place; rc_hi (regs8-15) emits next B
// with the SAME sigma permutation. 3->2 MFMA/block, 34->24 MFMA/tile, zero
// extra movs; ones-row passes via A[26][sig^-1(10)]=1. Intrinsic MFMA
// (hazard-safe), r17 config: single-variable change vs r17 (158us).
// Gates: absmax passes; MfmaUtil cyc -30%; FETCH ~24.8MB; WRITE 16384KB.

#define NPTS 4194304
#define NBLK 2048
#define NWAVES (NBLK * 4)           // 8192
#define NTILES (NPTS / 32)          // 131072
#define TPW (NTILES / NWAVES)       // 16 tiles per wave
#define NMM 24
#define ILP 2

typedef _Float16 h8 __attribute__((ext_vector_type(8)));
typedef float v8f __attribute__((ext_vector_type(8)));
typedef float v16f __attribute__((ext_vector_type(16)));
typedef unsigned u4v __attribute__((ext_vector_type(4)));

__device__ __forceinline__ v16f mm(h8 a, h8 b, v16f c) {
    return __builtin_amdgcn_mfma_f32_32x32x16_f16(a, b, c, 0, 0, 0);
}
__device__ __forceinline__ unsigned pkrtz(float a, float b) {
    return __builtin_bit_cast(unsigned, __builtin_amdgcn_cvt_pkrtz(a, b));
}
// relu+pack of D regs 0-7 (rows sigma(k)): B fragment, sigma order
__device__ __forceinline__ h8 rc_lo(v16f d) {
    v8f s = __builtin_shufflevector(d, d, 0, 1, 2, 3, 4, 5, 6, 7);
    v8f z = {0.f, 0.f, 0.f, 0.f, 0.f, 0.f, 0.f, 0.f};
    v8f m = __builtin_elementwise_max(s, z);
    u4v u;
    u.x = pkrtz(m[0], m[1]); u.y = pkrtz(m[2], m[3]);
    u.z = pkrtz(m[4], m[5]); u.w = pkrtz(m[6], m[7]);
    return __builtin_bit_cast(h8, u);
}
// relu+pack of D regs 8-15 (rows 16+sigma(k)): same sigma order
__device__ __forceinline__ h8 rc_hi(v16f d) {
    v8f s = __builtin_shufflevector(d, d, 8, 9, 10, 11, 12, 13, 14, 15);
    v8f z = {0.f, 0.f, 0.f, 0.f, 0.f, 0.f, 0.f, 0.f};
    v8f m = __builtin_elementwise_max(s, z);
    u4v u;
    u.x = pkrtz(m[0], m[1]); u.y = pkrtz(m[2], m[3]);
    u.z = pkrtz(m[4], m[5]); u.w = pkrtz(m[6], m[7]);
    return __builtin_bit_cast(h8, u);
}

// ---------------- prepack: fused A fragments, sigma-permuted K ---------------
// q=0: layer0 (k rows: x0,x1,x2 @ rr<3, bias col rr==3, pass A[10][rr==3]=1)
// q=1: layer1 dense (w1,b1, pass row 10)
// q=2+2l: fused block A: m0-9=Wr1^T|rr==10:Br1 ; m16-25=Wr2^T|rr==10:Br2+Br3;
//         m26,rr==10: 1 (ones pass)
// q=3+2l: W3 shifted: m16-25 = Wr3^T (rows 0-15 and 26 zero -> srcC passthru)
// q=22: layer8 dense (w8,b8, pass row 10)   q=23: out row m=0 (w9,b9)
__global__ __launch_bounds__(64) void prepack(
    const float* __restrict__ w0, const float* __restrict__ b0,
    const float* __restrict__ w1, const float* __restrict__ b1,
    const float* __restrict__ Wr1, const float* __restrict__ Br1,
    const float* __restrict__ Wr2, const float* __restrict__ Br2,
    const float* __restrict__ Wr3, const float* __restrict__ Br3,
    const float* __restrict__ w8, const float* __restrict__ b8,
    const float* __restrict__ w9, const float* __restrict__ b9,
    h8* __restrict__ tab)
{
    const int q = blockIdx.x, l = threadIdx.x;
    const int m = l & 31, g = l >> 5;
    h8 v;
#pragma unroll
    for (int j = 0; j < 8; ++j) {
        const int rr = (j & 3) + 8 * (j >> 2) + 4 * g;  // sigma(k)
        float a = 0.0f;
        if (q == 0) {
            if (m < 10 && rr < 3)        a = w0[rr * 10 + m];
            else if (m < 10 && rr == 3)  a = b0[m];
            else if (m == 10 && rr == 3) a = 1.0f;
        } else if (q == 1 || q == 22) {
            const float* W = (q == 1) ? w1 : w8;
            const float* B = (q == 1) ? b1 : b8;
            if (m < 10 && rr < 10)        a = W[rr * 10 + m];
            else if (m < 10 && rr == 10)  a = B[m];
            else if (m == 10 && rr == 10) a = 1.0f;
        } else if (q == 23) {
            if (m == 0 && rr < 10)       a = w9[rr];
            else if (m == 0 && rr == 10) a = b9[0];
        } else if (((q - 2) & 1) == 0) {           // fused W1|W2 block
            const int bl = (q - 2) >> 1;
            if (m < 10) {
                if (rr < 10)       a = Wr1[bl * 100 + rr * 10 + m];
                else if (rr == 10) a = Br1[bl * 10 + m];
            } else if (m >= 16 && m < 26) {
                if (rr < 10)       a = Wr2[bl * 100 + rr * 10 + (m - 16)];
                else if (rr == 10) a = Br2[bl * 10 + (m - 16)] + Br3[bl * 10 + (m - 16)];
            } else if (m == 26 && rr == 10) {
                a = 1.0f;                          // ones pass for next layer
            }
        } else {                                   // W3, output rows 16-25
            const int bl = (q - 3) >> 1;
            if (m >= 16 && m < 26 && rr < 10)
                a = Wr3[bl * 100 + rr * 10 + (m - 16)];
        }
        v[j] = (_Float16)a;
    }
    tab[q * 64 + l] = v;
}

// ---------------- main kernel: fused 24-MFMA chain, ILP=2 --------------------
__global__ __launch_bounds__(256, 2) void resnet_fwd(
    const float* __restrict__ x,
    const h8* __restrict__ tab,
    float* __restrict__ out)
{
    const int lane = threadIdx.x & 63;
    const int wv = blockIdx.x * 4 + (threadIdx.x >> 6);
    const int col = lane & 31;
    const bool lo = lane < 32;

    // weight fragments (24 x 16B/lane); allocator free to keep or remat
    h8 wA[NMM];
#pragma unroll
    for (int q = 0; q < NMM; ++q) wA[q] = tab[q * 64 + lane];

    // resident zero srcC
    v16f zero;
#pragma unroll
    for (int j = 0; j < 16; ++j) zero[j] = 0.0f;
    asm volatile("" : "+v"(zero));

    const long tile0 = (long)wv * TPW;

    for (int t = 0; t < TPW; t += ILP) {
        long base[ILP];
        h8 hh[ILP];

        // layer-0 B: lanes 0-31 carry (x0,x1,x2,1) in k-rows 0-3; rest zero
#pragma unroll
        for (int c = 0; c < ILP; ++c) {
            base[c] = (tile0 + t + c) * 32;
            float a0 = 0.f, a1 = 0.f, a2 = 0.f, a3 = 0.f;
            if (lo) {
                const float* p = x + (base[c] + col) * 3;
                a0 = p[0]; a1 = p[1]; a2 = p[2]; a3 = 1.0f;
            }
            u4v u;
            u.x = pkrtz(a0, a1); u.y = pkrtz(a2, a3); u.z = 0u; u.w = 0u;
            hh[c] = __builtin_bit_cast(h8, u);
        }

        // layer 0, layer 1
#pragma unroll
        for (int c = 0; c < ILP; ++c) hh[c] = rc_lo(mm(wA[0], hh[c], zero));
#pragma unroll
        for (int c = 0; c < ILP; ++c) hh[c] = rc_lo(mm(wA[1], hh[c], zero));

        // residual blocks: 2 MFMA each (fused W1|W2, then W3 onto rows 16-26)
#pragma unroll
        for (int bl = 0; bl < 10; ++bl) {
            v16f d12[ILP];
#pragma unroll
            for (int c = 0; c < ILP; ++c) d12[c] = mm(wA[2 + 2 * bl], hh[c], zero);
#pragma unroll
            for (int c = 0; c < ILP; ++c) {
                h8 t1 = rc_lo(d12[c]);
                d12[c] = mm(wA[3 + 2 * bl], t1, d12[c]);
            }
#pragma unroll
            for (int c = 0; c < ILP; ++c) hh[c] = rc_hi(d12[c]);
        }

        // layer 8
#pragma unroll
        for (int c = 0; c < ILP; ++c) hh[c] = rc_lo(mm(wA[22], hh[c], zero));

        // output layer: D row 0 (lanes 0-31, reg 0) = result for 32 points
#pragma unroll
        for (int c = 0; c < ILP; ++c) {
            v16f d = mm(wA[23], hh[c], zero);
            if (lo) out[base[c] + col] = d[0];
        }
    }
}

extern "C" void kernel_launch(void* const* d_in, const int* in_sizes, int n_in,
                              void* d_out, int out_size, void* d_ws, size_t ws_size,
                              hipStream_t stream)
{
    const float* x   = (const float*)d_in[0];
    const float* w0  = (const float*)d_in[1];
    const float* b0  = (const float*)d_in[2];
    const float* w1  = (const float*)d_in[3];
    const float* b1  = (const float*)d_in[4];
    const float* Wr1 = (const float*)d_in[5];
    const float* Br1 = (const float*)d_in[6];
    const float* Wr2 = (const float*)d_in[7];
    const float* Br2 = (const float*)d_in[8];
    const float* Wr3 = (const float*)d_in[9];
    const float* Br3 = (const float*)d_in[10];
    const float* w8  = (const float*)d_in[11];
    const float* b8  = (const float*)d_in[12];
    const float* w9  = (const float*)d_in[13];
    const float* b9  = (const float*)d_in[14];
    float* out = (float*)d_out;
    h8* tab = (h8*)d_ws;   // 24 * 64 * 16B = 24.6 KB scratch

    hipLaunchKernelGGL(prepack, dim3(NMM), dim3(64), 0, stream,
                       w0, b0, w1, b1, Wr1, Br1, Wr2, Br2, Wr3, Br3,
                       w8, b8, w9, b9, tab);

    hipLaunchKernelGGL(resnet_fwd, dim3(NBLK), dim3(256), 0, stream,
                       x, (const h8*)tab, out);
}